// Round 1
// baseline (1497.192 us; speedup 1.0000x reference)
//
#include <hip/hip_runtime.h>
#include <cstdint>
#include <cstddef>

#define B_ROWS 16384
#define S_ROWS 2048
#define D_DIM  512

typedef __attribute__((ext_vector_type(8))) short          s16x8;
typedef __attribute__((ext_vector_type(8))) unsigned short u16x8;
typedef __attribute__((ext_vector_type(4))) float          f32x4;

// ---------- bf16 split helpers ----------
static __device__ __forceinline__ unsigned short f2bf(float f) {
  unsigned int u = __builtin_bit_cast(unsigned int, f);
  u = (u + 0x7FFFu + ((u >> 16) & 1u)) >> 16;   // RNE
  return (unsigned short)u;
}
static __device__ __forceinline__ float bf2f(unsigned short h) {
  unsigned int u = ((unsigned int)h) << 16;
  return __builtin_bit_cast(float, u);
}
static __device__ __forceinline__ float mish_f(float z) {
  float sp = (z > 20.0f) ? z : log1pf(expf(z));
  return z * tanhf(sp);
}

static __device__ __forceinline__ f32x4 mfma16(s16x8 a, s16x8 b, f32x4 c) {
  return __builtin_amdgcn_mfma_f32_16x16x32_bf16(a, b, c, 0, 0, 0);
}

// async global->LDS, 16B per lane (dst is wave-uniform base; HW adds lane*16)
static __device__ __forceinline__ void gload16(unsigned short* lds_dst,
                                               const unsigned short* g_src) {
  __builtin_amdgcn_global_load_lds(
      (const __attribute__((address_space(1))) unsigned int*)g_src,
      (__attribute__((address_space(3))) unsigned int*)lds_dst,
      16, 0, 0);
}

// ---------- split fp32 -> (hi, lo) bf16 ----------
__global__ void split_kernel(const float* __restrict__ in,
                             unsigned short* __restrict__ hi,
                             unsigned short* __restrict__ lo, int n4) {
  const int stride = gridDim.x * blockDim.x;
  for (int i = blockIdx.x * blockDim.x + threadIdx.x; i < n4; i += stride) {
    const float4 v = ((const float4*)in)[i];
    float f[4] = {v.x, v.y, v.z, v.w};
    unsigned short hh[4], ll[4];
#pragma unroll
    for (int j = 0; j < 4; ++j) {
      hh[j] = f2bf(f[j]);
      ll[j] = f2bf(f[j] - bf2f(hh[j]));
    }
    ((ushort4*)hi)[i] = make_ushort4(hh[0], hh[1], hh[2], hh[3]);
    ((ushort4*)lo)[i] = make_ushort4(ll[0], ll[1], ll[2], ll[3]);
  }
}

// ---------- row squared-norms from (hi,lo), D=512, one wave per row ----------
__global__ void norm_kernel(const unsigned short* __restrict__ hi,
                            const unsigned short* __restrict__ lo,
                            float* __restrict__ out, int rows) {
  const int gw = (int)((blockIdx.x * blockDim.x + threadIdx.x) >> 6);
  const int l  = threadIdx.x & 63;
  if (gw >= rows) return;
  const size_t base = (size_t)gw * D_DIM + (size_t)l * 8;
  const u16x8 h8 = *(const u16x8*)(hi + base);
  const u16x8 l8 = *(const u16x8*)(lo + base);
  float s = 0.f;
#pragma unroll
  for (int j = 0; j < 8; ++j) {
    float v = bf2f(h8[j]) + bf2f(l8[j]);
    s += v * v;
  }
#pragma unroll
  for (int m = 32; m; m >>= 1) s += __shfl_xor(s, m, 64);
  if (l == 0) out[gw] = s;
}

// ---------- split-fp32 GEMM: C = epi(A @ B^T) ----------
// A [M,K], B [N,K] row-major as (hi,lo) bf16 pairs. 128x128 tile, BK=32,
// 4 waves (2x2 of 64x64), mfma 16x16x32, 3 passes (hh, hl, lh).
// EPI: 0 = bias+mish -> split out   (dml layer 1)
//      1 = bias       -> split out  (dml layer 2)
//      2 = rbf        -> split out  (K = exp(-sqrt(max(na+nb-2dot,0))))
//      3 = mish       -> split out  (nystrom layer 1)
//      4 = plain      -> f32 out    (final)
#define BKT 32

template <int EPI>
__global__ __launch_bounds__(256) void gemm_split(
    const unsigned short* __restrict__ Ahi, const unsigned short* __restrict__ Alo,
    const unsigned short* __restrict__ Bhi, const unsigned short* __restrict__ Blo,
    const float* __restrict__ bias, const float* __restrict__ nrmA,
    const float* __restrict__ nrmB,
    unsigned short* __restrict__ Chi, unsigned short* __restrict__ Clo,
    float* __restrict__ Cf, int M, int N, int K) {
  __shared__ __align__(16) unsigned short lds[4 * 128 * BKT];  // 32 KiB
  unsigned short* tAh = lds;
  unsigned short* tAl = lds + 128 * BKT;
  unsigned short* tBh = lds + 2 * 128 * BKT;
  unsigned short* tBl = lds + 3 * 128 * BKT;

  const int tid = threadIdx.x;
  const int w = tid >> 6;          // wave 0..3
  const int l = tid & 63;
  const int nTm = M >> 7;
  const int tm = (int)(blockIdx.x) % nTm;
  const int tn = (int)(blockIdx.x) / nTm;
  const int rowA0 = tm << 7;
  const int rowB0 = tn << 7;

  const int wm = w >> 1, wn = w & 1;
  const int fr = l & 15, fg = l >> 4;

  f32x4 acc[4][4];
#pragma unroll
  for (int i = 0; i < 4; ++i)
#pragma unroll
    for (int j = 0; j < 4; ++j) acc[i][j] = (f32x4){0.f, 0.f, 0.f, 0.f};

  // staging: lane l writes LDS slot (row = base+l/4, chunk = l&3); LDS slot
  // (row, c) holds global 16B-chunk c ^ (row&3)  -> fragment reads spread
  // uniformly across all 8 bank quads.
  const int srow   = l >> 2;
  const int gchunk = (l & 3) ^ (srow & 3);

  const int nk = K >> 5;
  for (int kt = 0; kt < nk; ++kt) {
    const int k0 = kt << 5;
#pragma unroll
    for (int j = 0; j < 2; ++j) {
      const int rl = w * 32 + j * 16;        // wave-uniform LDS row base
      const int gr = rl + srow;              // per-lane tile row
      const size_t ga = (size_t)(rowA0 + gr) * (size_t)K + (size_t)(k0 + gchunk * 8);
      const size_t gb = (size_t)(rowB0 + gr) * (size_t)K + (size_t)(k0 + gchunk * 8);
      gload16(tAh + rl * BKT, Ahi + ga);
      gload16(tAl + rl * BKT, Alo + ga);
      gload16(tBh + rl * BKT, Bhi + gb);
      gload16(tBl + rl * BKT, Blo + gb);
    }
    __syncthreads();

    s16x8 ah[4], al[4], bh[4], bl[4];
#pragma unroll
    for (int mi = 0; mi < 4; ++mi) {
      const int r = wm * 64 + mi * 16 + fr;
      const int c = (fg ^ (r & 3)) << 3;
      ah[mi] = *(const s16x8*)&tAh[r * BKT + c];
      al[mi] = *(const s16x8*)&tAl[r * BKT + c];
    }
#pragma unroll
    for (int ni = 0; ni < 4; ++ni) {
      const int r = wn * 64 + ni * 16 + fr;
      const int c = (fg ^ (r & 3)) << 3;
      bh[ni] = *(const s16x8*)&tBh[r * BKT + c];
      bl[ni] = *(const s16x8*)&tBl[r * BKT + c];
    }
#pragma unroll
    for (int mi = 0; mi < 4; ++mi)
#pragma unroll
      for (int ni = 0; ni < 4; ++ni) {
        acc[mi][ni] = mfma16(al[mi], bh[ni], acc[mi][ni]);
        acc[mi][ni] = mfma16(ah[mi], bl[ni], acc[mi][ni]);
        acc[mi][ni] = mfma16(ah[mi], bh[ni], acc[mi][ni]);
      }
    __syncthreads();
  }

  // epilogue: C/D layout col = lane&15, row = (lane>>4)*4 + reg
  const int rowBase = rowA0 + wm * 64;
  const int colBase = rowB0 + wn * 64;
#pragma unroll
  for (int mi = 0; mi < 4; ++mi) {
#pragma unroll
    for (int ni = 0; ni < 4; ++ni) {
      const int col = colBase + ni * 16 + fr;
      float badd = 0.f;
      if constexpr (EPI == 0 || EPI == 1) badd = bias[col];
      float nB = 0.f;
      if constexpr (EPI == 2) nB = nrmB[col];
#pragma unroll
      for (int r = 0; r < 4; ++r) {
        const int row = rowBase + mi * 16 + fg * 4 + r;
        float v = acc[mi][ni][r];
        if constexpr (EPI == 0 || EPI == 1) v += badd;
        if constexpr (EPI == 2) {
          float d2 = nrmA[row] + nB - 2.f * v;
          v = expf(-sqrtf(fmaxf(d2, 0.f)));
        }
        if constexpr (EPI == 0 || EPI == 3) v = mish_f(v);
        const size_t o = (size_t)row * (size_t)N + (size_t)col;
        if constexpr (EPI == 4) {
          Cf[o] = v;
        } else {
          unsigned short h = f2bf(v);
          Chi[o] = h;
          Clo[o] = f2bf(v - bf2f(h));
        }
      }
    }
  }
}

template <int EPI>
static void launch_gemm(const unsigned short* Ahi, const unsigned short* Alo,
                        const unsigned short* Bhi, const unsigned short* Blo,
                        const float* bias, const float* nrmA, const float* nrmB,
                        unsigned short* Chi, unsigned short* Clo, float* Cf,
                        int M, int N, int K, hipStream_t stream) {
  dim3 grid((unsigned)((M >> 7) * (N >> 7)));
  gemm_split<EPI><<<grid, dim3(256), 0, stream>>>(Ahi, Alo, Bhi, Blo, bias,
                                                  nrmA, nrmB, Chi, Clo, Cf, M, N, K);
}

static int grid_for(int n4) {
  int g = (n4 + 255) / 256;
  return g > 4096 ? 4096 : g;
}

extern "C" void kernel_launch(void* const* d_in, const int* in_sizes, int n_in,
                              void* d_out, int out_size, void* d_ws, size_t ws_size,
                              hipStream_t stream) {
  const float* x       = (const float*)d_in[0];
  const float* samples = (const float*)d_in[1];
  const float* W1      = (const float*)d_in[2];
  const float* b1      = (const float*)d_in[3];
  const float* W2      = (const float*)d_in[4];
  const float* b2      = (const float*)d_in[5];
  const float* Wn1     = (const float*)d_in[6];
  const float* Wn2     = (const float*)d_in[7];
  float* outF = (float*)d_out;

  if (ws_size < 167845888ull) return;  // clean visible failure if ws too small

  // ---- d_out region (134,217,728 B) doubles as scratch ----
  char* ob = (char*)d_out;
  unsigned short* xhi  = (unsigned short*)(ob + 0);          // dead after dml(x) L1
  unsigned short* xlo  = (unsigned short*)(ob + 16777216);
  unsigned short* t1hi = (unsigned short*)(ob + 33554432);   // dead after dml(x) L2
  unsigned short* t1lo = (unsigned short*)(ob + 50331648);
  unsigned short* t2hi = (unsigned short*)(ob + 67108864);   // dead after dml(s) L2
  unsigned short* t2lo = (unsigned short*)(ob + 69206016);
  unsigned short* Khi  = (unsigned short*)(ob + 0);          // written by RBF gemm
  unsigned short* Klo  = (unsigned short*)(ob + 67108864);   // dead before final write

  // ---- workspace ----
  char* wb = (char*)d_ws;
  unsigned short* hhi  = (unsigned short*)(wb + 0);          // written at nystrom L1
  unsigned short* hlo  = (unsigned short*)(wb + 67108864);
  //   early overlay inside h region (all dead before h is written):
  unsigned short* xdhi = (unsigned short*)(wb + 0);
  unsigned short* xdlo = (unsigned short*)(wb + 16777216);
  unsigned short* snhi = (unsigned short*)(wb + 33554432);
  unsigned short* snlo = (unsigned short*)(wb + 35651584);
  unsigned short* samhi= (unsigned short*)(wb + 37748736);
  unsigned short* samlo= (unsigned short*)(wb + 39845888);
  unsigned short* W1hi = (unsigned short*)(wb + 41943040);
  unsigned short* W1lo = (unsigned short*)(wb + 42467328);
  unsigned short* W2hi = (unsigned short*)(wb + 42991616);
  unsigned short* W2lo = (unsigned short*)(wb + 43515904);
  //   persistent region:
  unsigned short* Wn1hi= (unsigned short*)(wb + 134217728);
  unsigned short* Wn1lo= (unsigned short*)(wb + 142606336);
  unsigned short* Wn2hi= (unsigned short*)(wb + 150994944);
  unsigned short* Wn2lo= (unsigned short*)(wb + 159383552);
  float* nx            = (float*)(wb + 167772160);
  float* ns            = (float*)(wb + 167837696);

  const dim3 tpb(256);

  // split inputs into (hi, lo) bf16
  {
    int n4;
    n4 = B_ROWS * D_DIM / 4;
    split_kernel<<<grid_for(n4), tpb, 0, stream>>>(x, xhi, xlo, n4);
    n4 = S_ROWS * D_DIM / 4;
    split_kernel<<<grid_for(n4), tpb, 0, stream>>>(samples, samhi, samlo, n4);
    n4 = D_DIM * D_DIM / 4;
    split_kernel<<<grid_for(n4), tpb, 0, stream>>>(W1, W1hi, W1lo, n4);
    split_kernel<<<grid_for(n4), tpb, 0, stream>>>(W2, W2hi, W2lo, n4);
    n4 = S_ROWS * S_ROWS / 4;
    split_kernel<<<grid_for(n4), tpb, 0, stream>>>(Wn1, Wn1hi, Wn1lo, n4);
    split_kernel<<<grid_for(n4), tpb, 0, stream>>>(Wn2, Wn2hi, Wn2lo, n4);
  }

  // dml(x): t1 = mish(x@W1^T + b1); xd = t1@W2^T + b2
  launch_gemm<0>(xhi, xlo, W1hi, W1lo, b1, nullptr, nullptr, t1hi, t1lo, nullptr,
                 B_ROWS, D_DIM, D_DIM, stream);
  launch_gemm<1>(t1hi, t1lo, W2hi, W2lo, b2, nullptr, nullptr, xdhi, xdlo, nullptr,
                 B_ROWS, D_DIM, D_DIM, stream);
  // dml(samples)
  launch_gemm<0>(samhi, samlo, W1hi, W1lo, b1, nullptr, nullptr, t2hi, t2lo, nullptr,
                 S_ROWS, D_DIM, D_DIM, stream);
  launch_gemm<1>(t2hi, t2lo, W2hi, W2lo, b2, nullptr, nullptr, snhi, snlo, nullptr,
                 S_ROWS, D_DIM, D_DIM, stream);

  // row norms (from the same hi+lo values the MFMA consumes)
  norm_kernel<<<dim3(B_ROWS / 4), tpb, 0, stream>>>(xdhi, xdlo, nx, B_ROWS);
  norm_kernel<<<dim3(S_ROWS / 4), tpb, 0, stream>>>(snhi, snlo, ns, S_ROWS);

  // K = exp(-sqrt(max(nx + ns - 2 * xd@sn^T, 0)))
  launch_gemm<2>(xdhi, xdlo, snhi, snlo, nullptr, nx, ns, Khi, Klo, nullptr,
                 B_ROWS, S_ROWS, D_DIM, stream);

  // h = mish(K@Wn1^T)
  launch_gemm<3>(Khi, Klo, Wn1hi, Wn1lo, nullptr, nullptr, nullptr, hhi, hlo, nullptr,
                 B_ROWS, S_ROWS, S_ROWS, stream);

  // out = h@Wn2^T
  launch_gemm<4>(hhi, hlo, Wn2hi, Wn2lo, nullptr, nullptr, nullptr, nullptr, nullptr,
                 outF, B_ROWS, S_ROWS, S_ROWS, stream);
}

// Round 2
// 1474.859 us; speedup vs baseline: 1.0151x; 1.0151x over previous
//
#include <hip/hip_runtime.h>
#include <cstdint>
#include <cstddef>

#define B_ROWS 16384
#define S_ROWS 2048
#define D_DIM  512

typedef __attribute__((ext_vector_type(8))) short          s16x8;
typedef __attribute__((ext_vector_type(8))) unsigned short u16x8;
typedef __attribute__((ext_vector_type(4))) float          f32x4;

// ---------- bf16 split helpers ----------
static __device__ __forceinline__ unsigned short f2bf(float f) {
  unsigned int u = __builtin_bit_cast(unsigned int, f);
  u = (u + 0x7FFFu + ((u >> 16) & 1u)) >> 16;   // RNE
  return (unsigned short)u;
}
static __device__ __forceinline__ float bf2f(unsigned short h) {
  unsigned int u = ((unsigned int)h) << 16;
  return __builtin_bit_cast(float, u);
}
static __device__ __forceinline__ float mish_f(float z) {
  float sp = (z > 20.0f) ? z : log1pf(expf(z));
  return z * tanhf(sp);
}

static __device__ __forceinline__ f32x4 mfma16(s16x8 a, s16x8 b, f32x4 c) {
  return __builtin_amdgcn_mfma_f32_16x16x32_bf16(a, b, c, 0, 0, 0);
}

// async global->LDS, 16B per lane (dst is wave-uniform base; HW adds lane*16)
static __device__ __forceinline__ void gload16(unsigned short* lds_dst,
                                               const unsigned short* g_src) {
  __builtin_amdgcn_global_load_lds(
      (const __attribute__((address_space(1))) unsigned int*)g_src,
      (__attribute__((address_space(3))) unsigned int*)lds_dst,
      16, 0, 0);
}

// ---------- split fp32 -> (hi, lo) bf16 ----------
__global__ void split_kernel(const float* __restrict__ in,
                             unsigned short* __restrict__ hi,
                             unsigned short* __restrict__ lo, int n4) {
  const int stride = gridDim.x * blockDim.x;
  for (int i = blockIdx.x * blockDim.x + threadIdx.x; i < n4; i += stride) {
    const float4 v = ((const float4*)in)[i];
    float f[4] = {v.x, v.y, v.z, v.w};
    unsigned short hh[4], ll[4];
#pragma unroll
    for (int j = 0; j < 4; ++j) {
      hh[j] = f2bf(f[j]);
      ll[j] = f2bf(f[j] - bf2f(hh[j]));
    }
    ((ushort4*)hi)[i] = make_ushort4(hh[0], hh[1], hh[2], hh[3]);
    ((ushort4*)lo)[i] = make_ushort4(ll[0], ll[1], ll[2], ll[3]);
  }
}

// ---------- row squared-norms from (hi,lo), D=512, one wave per row ----------
__global__ void norm_kernel(const unsigned short* __restrict__ hi,
                            const unsigned short* __restrict__ lo,
                            float* __restrict__ out, int rows) {
  const int gw = (int)((blockIdx.x * blockDim.x + threadIdx.x) >> 6);
  const int l  = threadIdx.x & 63;
  if (gw >= rows) return;
  const size_t base = (size_t)gw * D_DIM + (size_t)l * 8;
  const u16x8 h8 = *(const u16x8*)(hi + base);
  const u16x8 l8 = *(const u16x8*)(lo + base);
  float s = 0.f;
#pragma unroll
  for (int j = 0; j < 8; ++j) {
    float v = bf2f(h8[j]) + bf2f(l8[j]);
    s += v * v;
  }
#pragma unroll
  for (int m = 32; m; m >>= 1) s += __shfl_xor(s, m, 64);
  if (l == 0) out[gw] = s;
}

// ---------- split-fp32 GEMM: C = epi(A @ B^T) ----------
// A [M,K], B [N,K] row-major as (hi,lo) bf16 pairs. 128x128 tile, BK=32,
// 4 waves (2x2 of 64x64), mfma 16x16x32, 3 passes (hh, hl, lh).
//
// LDS layout (per operand): 128 rows x 128 B. Row r holds 8 16B chunks:
// logical chunk c (c<4: hi elements c*8..; c>=4: lo elements (c-4)*8..)
// stored at position pos = c ^ (r&7).  128 B row stride == bank wrap, and
// the XOR gives each 16-lane quarter 8 distinct 4-bank quads x2 lanes
// (the free minimum) on both hi and lo fragment reads.
// Staging is linear in LDS (global_load_lds constraint); the permutation
// is applied on the per-lane GLOBAL source address (rule #21).
//
// EPI: 0 = bias+mish -> split out   (dml layer 1)
//      1 = bias       -> split out  (dml layer 2)
//      2 = rbf        -> split out  (K = exp(-sqrt(max(na+nb-2dot,0))))
//      3 = mish       -> split out  (nystrom layer 1)
//      4 = plain      -> f32 out    (final)

template <int EPI>
__global__ __launch_bounds__(256) void gemm_split(
    const unsigned short* __restrict__ Ahi, const unsigned short* __restrict__ Alo,
    const unsigned short* __restrict__ Bhi, const unsigned short* __restrict__ Blo,
    const float* __restrict__ bias, const float* __restrict__ nrmA,
    const float* __restrict__ nrmB,
    unsigned short* __restrict__ Chi, unsigned short* __restrict__ Clo,
    float* __restrict__ Cf, int M, int N, int K) {
  // 2 tiles (A,B) x 128 rows x 64 shorts(128 B) = 32 KiB
  __shared__ __align__(16) unsigned short lds[2 * 128 * 64];
  unsigned short* tA = lds;
  unsigned short* tB = lds + 128 * 64;

  const int tid = threadIdx.x;
  const int w = tid >> 6;          // wave 0..3
  const int l = tid & 63;

  // ---- block mapping: bijective XCD swizzle (m204) + tn-fast order ----
  const int nwg = (int)gridDim.x;
  {
  }
  const int q8 = nwg >> 3, r8 = nwg & 7;
  const int xcd = (int)blockIdx.x & 7, boff = (int)blockIdx.x >> 3;
  const int swz = (xcd < r8 ? xcd * (q8 + 1) : r8 * (q8 + 1) + (xcd - r8) * q8) + boff;
  const int nTn = N >> 7;
  const int tm = swz / nTn;
  const int tn = swz - tm * nTn;
  const int rowA0 = tm << 7;
  const int rowB0 = tn << 7;

  const int wm = w >> 1, wn = w & 1;
  const int fr = l & 15, fg = l >> 4;

  f32x4 acc[4][4];
#pragma unroll
  for (int i = 0; i < 4; ++i)
#pragma unroll
    for (int j = 0; j < 4; ++j) acc[i][j] = (f32x4){0.f, 0.f, 0.f, 0.f};

  // ---- staging source pre-swizzle ----
  // lane l stages LDS slot (row = base + l/8, pos = l&7); the logical chunk
  // there is c = pos ^ (row&7) = (l&7) ^ ((l>>3)&7)  (bases are multiples of 8)
  const int pos   = l & 7;
  const int rsub  = (l >> 3) & 7;
  const int c     = pos ^ rsub;
  const bool isHi = (c < 4);
  const int celem = (c & 3) << 3;            // element offset within hi/lo row

  const unsigned short* srcA[4];
  const unsigned short* srcB[4];
  unsigned short* dstA[4];
  unsigned short* dstB[4];
#pragma unroll
  for (int j = 0; j < 4; ++j) {
    const int rl = w * 32 + j * 8;           // wave-uniform LDS row base
    const int gr = rl + (l >> 3);            // per-lane tile row
    srcA[j] = (isHi ? Ahi : Alo) + (size_t)(rowA0 + gr) * (size_t)K + celem;
    srcB[j] = (isHi ? Bhi : Blo) + (size_t)(rowB0 + gr) * (size_t)K + celem;
    dstA[j] = tA + rl * 64;
    dstB[j] = tB + rl * 64;
  }

  // fragment read addressing: row r -> byte r*128 + (fg^(r&7))*16; since all
  // sub-tile row bases are multiples of 16, r&7 == fr&7 -> per-lane constant.
  const int pbyte = (fg ^ (fr & 7)) << 4;    // hi chunk position * 16 B
  const char* tAc = (const char*)tA;
  const char* tBc = (const char*)tB;

  const int nk = K >> 5;
  for (int kt = 0; kt < nk; ++kt) {
    const int k0 = kt << 5;
#pragma unroll
    for (int j = 0; j < 4; ++j) {
      gload16(dstA[j], srcA[j] + k0);
      gload16(dstB[j], srcB[j] + k0);
    }
    __syncthreads();

    s16x8 ah[4], al[4], bh[4], bl[4];
#pragma unroll
    for (int mi = 0; mi < 4; ++mi) {
      const int base = ((wm << 6) + (mi << 4) + fr) << 7;  // row * 128 B
      ah[mi] = *(const s16x8*)(tAc + (base + pbyte));
      al[mi] = *(const s16x8*)(tAc + ((base + pbyte) ^ 64));
    }
#pragma unroll
    for (int ni = 0; ni < 4; ++ni) {
      const int base = ((wn << 6) + (ni << 4) + fr) << 7;
      bh[ni] = *(const s16x8*)(tBc + (base + pbyte));
      bl[ni] = *(const s16x8*)(tBc + ((base + pbyte) ^ 64));
    }
#pragma unroll
    for (int mi = 0; mi < 4; ++mi)
#pragma unroll
      for (int ni = 0; ni < 4; ++ni) {
        acc[mi][ni] = mfma16(al[mi], bh[ni], acc[mi][ni]);
        acc[mi][ni] = mfma16(ah[mi], bl[ni], acc[mi][ni]);
        acc[mi][ni] = mfma16(ah[mi], bh[ni], acc[mi][ni]);
      }
    __syncthreads();
  }

  // epilogue: C/D layout col = lane&15, row = (lane>>4)*4 + reg
  const int rowBase = rowA0 + wm * 64;
  const int colBase = rowB0 + wn * 64;
#pragma unroll
  for (int mi = 0; mi < 4; ++mi) {
#pragma unroll
    for (int ni = 0; ni < 4; ++ni) {
      const int col = colBase + ni * 16 + fr;
      float badd = 0.f;
      if constexpr (EPI == 0 || EPI == 1) badd = bias[col];
      float nB = 0.f;
      if constexpr (EPI == 2) nB = nrmB[col];
#pragma unroll
      for (int r = 0; r < 4; ++r) {
        const int row = rowBase + mi * 16 + fg * 4 + r;
        float v = acc[mi][ni][r];
        if constexpr (EPI == 0 || EPI == 1) v += badd;
        if constexpr (EPI == 2) {
          float d2 = nrmA[row] + nB - 2.f * v;
          v = expf(-sqrtf(fmaxf(d2, 0.f)));
        }
        if constexpr (EPI == 0 || EPI == 3) v = mish_f(v);
        const size_t o = (size_t)row * (size_t)N + (size_t)col;
        if constexpr (EPI == 4) {
          Cf[o] = v;
        } else {
          unsigned short h = f2bf(v);
          Chi[o] = h;
          Clo[o] = f2bf(v - bf2f(h));
        }
      }
    }
  }
}

template <int EPI>
static void launch_gemm(const unsigned short* Ahi, const unsigned short* Alo,
                        const unsigned short* Bhi, const unsigned short* Blo,
                        const float* bias, const float* nrmA, const float* nrmB,
                        unsigned short* Chi, unsigned short* Clo, float* Cf,
                        int M, int N, int K, hipStream_t stream) {
  dim3 grid((unsigned)((M >> 7) * (N >> 7)));
  gemm_split<EPI><<<grid, dim3(256), 0, stream>>>(Ahi, Alo, Bhi, Blo, bias,
                                                  nrmA, nrmB, Chi, Clo, Cf, M, N, K);
}

static int grid_for(int n4) {
  int g = (n4 + 255) / 256;
  return g > 4096 ? 4096 : g;
}

extern "C" void kernel_launch(void* const* d_in, const int* in_sizes, int n_in,
                              void* d_out, int out_size, void* d_ws, size_t ws_size,
                              hipStream_t stream) {
  const float* x       = (const float*)d_in[0];
  const float* samples = (const float*)d_in[1];
  const float* W1      = (const float*)d_in[2];
  const float* b1      = (const float*)d_in[3];
  const float* W2      = (const float*)d_in[4];
  const float* b2      = (const float*)d_in[5];
  const float* Wn1     = (const float*)d_in[6];
  const float* Wn2     = (const float*)d_in[7];
  float* outF = (float*)d_out;

  if (ws_size < 167845888ull) return;  // clean visible failure if ws too small

  // ---- d_out region (134,217,728 B) doubles as scratch ----
  char* ob = (char*)d_out;
  unsigned short* xhi  = (unsigned short*)(ob + 0);          // dead after dml(x) L1
  unsigned short* xlo  = (unsigned short*)(ob + 16777216);
  unsigned short* t1hi = (unsigned short*)(ob + 33554432);   // dead after dml(x) L2
  unsigned short* t1lo = (unsigned short*)(ob + 50331648);
  unsigned short* t2hi = (unsigned short*)(ob + 67108864);   // dead after dml(s) L2
  unsigned short* t2lo = (unsigned short*)(ob + 69206016);
  unsigned short* Khi  = (unsigned short*)(ob + 0);          // written by RBF gemm
  unsigned short* Klo  = (unsigned short*)(ob + 67108864);   // dead before final write

  // ---- workspace ----
  char* wb = (char*)d_ws;
  unsigned short* hhi  = (unsigned short*)(wb + 0);          // written at nystrom L1
  unsigned short* hlo  = (unsigned short*)(wb + 67108864);
  //   early overlay inside h region (all dead before h is written):
  unsigned short* xdhi = (unsigned short*)(wb + 0);
  unsigned short* xdlo = (unsigned short*)(wb + 16777216);
  unsigned short* snhi = (unsigned short*)(wb + 33554432);
  unsigned short* snlo = (unsigned short*)(wb + 35651584);
  unsigned short* samhi= (unsigned short*)(wb + 37748736);
  unsigned short* samlo= (unsigned short*)(wb + 39845888);
  unsigned short* W1hi = (unsigned short*)(wb + 41943040);
  unsigned short* W1lo = (unsigned short*)(wb + 42467328);
  unsigned short* W2hi = (unsigned short*)(wb + 42991616);
  unsigned short* W2lo = (unsigned short*)(wb + 43515904);
  //   persistent region:
  unsigned short* Wn1hi= (unsigned short*)(wb + 134217728);
  unsigned short* Wn1lo= (unsigned short*)(wb + 142606336);
  unsigned short* Wn2hi= (unsigned short*)(wb + 150994944);
  unsigned short* Wn2lo= (unsigned short*)(wb + 159383552);
  float* nx            = (float*)(wb + 167772160);
  float* ns            = (float*)(wb + 167837696);

  const dim3 tpb(256);

  // split inputs into (hi, lo) bf16
  {
    int n4;
    n4 = B_ROWS * D_DIM / 4;
    split_kernel<<<grid_for(n4), tpb, 0, stream>>>(x, xhi, xlo, n4);
    n4 = S_ROWS * D_DIM / 4;
    split_kernel<<<grid_for(n4), tpb, 0, stream>>>(samples, samhi, samlo, n4);
    n4 = D_DIM * D_DIM / 4;
    split_kernel<<<grid_for(n4), tpb, 0, stream>>>(W1, W1hi, W1lo, n4);
    split_kernel<<<grid_for(n4), tpb, 0, stream>>>(W2, W2hi, W2lo, n4);
    n4 = S_ROWS * S_ROWS / 4;
    split_kernel<<<grid_for(n4), tpb, 0, stream>>>(Wn1, Wn1hi, Wn1lo, n4);
    split_kernel<<<grid_for(n4), tpb, 0, stream>>>(Wn2, Wn2hi, Wn2lo, n4);
  }

  // dml(x): t1 = mish(x@W1^T + b1); xd = t1@W2^T + b2
  launch_gemm<0>(xhi, xlo, W1hi, W1lo, b1, nullptr, nullptr, t1hi, t1lo, nullptr,
                 B_ROWS, D_DIM, D_DIM, stream);
  launch_gemm<1>(t1hi, t1lo, W2hi, W2lo, b2, nullptr, nullptr, xdhi, xdlo, nullptr,
                 B_ROWS, D_DIM, D_DIM, stream);
  // dml(samples)
  launch_gemm<0>(samhi, samlo, W1hi, W1lo, b1, nullptr, nullptr, t2hi, t2lo, nullptr,
                 S_ROWS, D_DIM, D_DIM, stream);
  launch_gemm<1>(t2hi, t2lo, W2hi, W2lo, b2, nullptr, nullptr, snhi, snlo, nullptr,
                 S_ROWS, D_DIM, D_DIM, stream);

  // row norms (from the same hi+lo values the MFMA consumes)
  norm_kernel<<<dim3(B_ROWS / 4), tpb, 0, stream>>>(xdhi, xdlo, nx, B_ROWS);
  norm_kernel<<<dim3(S_ROWS / 4), tpb, 0, stream>>>(snhi, snlo, ns, S_ROWS);

  // K = exp(-sqrt(max(nx + ns - 2 * xd@sn^T, 0)))
  launch_gemm<2>(xdhi, xdlo, snhi, snlo, nullptr, nx, ns, Khi, Klo, nullptr,
                 B_ROWS, S_ROWS, D_DIM, stream);

  // h = mish(K@Wn1^T)
  launch_gemm<3>(Khi, Klo, Wn1hi, Wn1lo, nullptr, nullptr, nullptr, hhi, hlo, nullptr,
                 B_ROWS, S_ROWS, S_ROWS, stream);

  // out = h@Wn2^T
  launch_gemm<4>(hhi, hlo, Wn2hi, Wn2lo, nullptr, nullptr, nullptr, nullptr, nullptr,
                 outF, B_ROWS, S_ROWS, S_ROWS, stream);
}